// Round 14
// baseline (386.987 us; speedup 1.0000x reference)
//
#include <hip/hip_runtime.h>

#define CSC 64
#define CVC 32
#define HIDC 128
#define NWC 224
#define RBFD 32
#define CUTF 5.0f

typedef __attribute__((ext_vector_type(8))) short bfrag8;
typedef __attribute__((ext_vector_type(4))) float facc4;

__device__ __forceinline__ unsigned short f2bf(float x) {
    union { float f; unsigned int u; } a; a.f = x;
    unsigned int u = a.u;
    return (unsigned short)((u + 0x7fffu + ((u >> 16) & 1u)) >> 16);
}
__device__ __forceinline__ float bf2f(unsigned int u16) {
    union { float f; unsigned int v; } x; x.v = u16 << 16; return x.f;
}

__device__ __forceinline__ float siluf(float x) { return x / (1.0f + __expf(-x)); }
__device__ __forceinline__ float sigmf(float x) { return 1.0f / (1.0f + __expf(-x)); }

// ---------------- CSR build ------------------------------------------------------------------
__global__ __launch_bounds__(256) void eae_zero_int(int* __restrict__ p, int n) {
    int i = blockIdx.x * 256 + threadIdx.x;
    if (i < n) p[i] = 0;
}

__global__ __launch_bounds__(256) void eae_hist_kernel(const int* __restrict__ edge_dst,
                                                       int* __restrict__ cnt, int E) {
    int e = blockIdx.x * 256 + threadIdx.x;
    if (e < E) atomicAdd(&cnt[edge_dst[e]], 1);
}

__global__ __launch_bounds__(256) void eae_scan_kernel(const int* __restrict__ cnt,
                                                       int* __restrict__ row_ptr,
                                                       int* __restrict__ cursor, int BN) {
    __shared__ int part[256];
    int t = threadIdx.x;
    int per = (BN + 255) / 256;
    int base = t * per;
    int local[16];
    int lsum = 0;
    for (int i = 0; i < per; ++i) {
        int idx = base + i;
        int c = (idx < BN) ? cnt[idx] : 0;
        local[i] = c; lsum += c;
    }
    part[t] = lsum;
    __syncthreads();
    if (t == 0) {
        int run = 0;
        for (int i = 0; i < 256; ++i) { int v = part[i]; part[i] = run; run += v; }
    }
    __syncthreads();
    int run = part[t];
    for (int i = 0; i < per; ++i) {
        int idx = base + i;
        if (idx < BN) { row_ptr[idx] = run; cursor[idx] = run; run += local[i]; }
    }
    if (t == 255) row_ptr[BN] = run;
}

// scatter + per-edge precompute: y (sqrt3-scaled unit vec) + env + 32 RBF bf16
__global__ __launch_bounds__(256) void eae_scatter_kernel(
    const int* __restrict__ edge_dst, const int* __restrict__ edge_src,
    const float* __restrict__ edge_weight, const float* __restrict__ edge_vec,
    int* __restrict__ cursor, float4* __restrict__ edata, int* __restrict__ esrc,
    unsigned short* __restrict__ rbf_g, int E) {
    int e = blockIdx.x * 256 + threadIdx.x;
    if (e < E) {
        int pos = atomicAdd(&cursor[edge_dst[e]], 1);
        const float SQ3 = 1.7320508075688772f;
        const float PIF = 3.14159265358979323846f;
        const float delta = CUTF / (RBFD - 1);
        const float inv_delta = 1.0f / delta;
        float el = edge_weight[e];
        float inv = 1.0f / fmaxf(el, 1e-8f);
        float4 d;
        d.x = SQ3 * edge_vec[3 * e + 0] * inv;
        d.y = SQ3 * edge_vec[3 * e + 1] * inv;
        d.z = SQ3 * edge_vec[3 * e + 2] * inv;
        d.w = (el < CUTF) ? 0.5f * (__cosf(PIF * el / CUTF) + 1.0f) : 0.0f;
        edata[pos] = d;
        esrc[pos] = edge_src[e];
        float dd = fminf(el, CUTF) * inv_delta;
        unsigned short* rp = rbf_g + (size_t)pos * RBFD;
        #pragma unroll
        for (int k = 0; k < RBFD; ++k) {
            float x = dd - (float)k;
            rp[k] = f2bf(__expf(-0.5f * x * x));
        }
    }
}

// ---------------- weight packing: bf16 MFMA fragment layout (once per call) ------------------
__global__ __launch_bounds__(64) void eae_pack_kernel(
    const float* __restrict__ W1, const float* __restrict__ W2,
    unsigned short* __restrict__ W1P, unsigned short* __restrict__ W2P)
{
    int b = blockIdx.x;
    int lane = threadIdx.x;
    int t4 = lane >> 4, lr = lane & 15;
    if (b < 24) {
        int blk = b >> 3, mt = b & 7;
        const float* W1b = W1 + blk * 32 * 128;
        unsigned short* dst = W1P + ((size_t)b * 64 + lane) * 8;
        #pragma unroll
        for (int i = 0; i < 8; ++i) {
            int k = 8 * t4 + i;
            dst[i] = f2bf(W1b[k * HIDC + 16 * mt + lr]);
        }
    } else {
        int idx = b - 24;
        int blk = idx >> 6, rem = idx & 63;
        int mt = rem >> 2, ks = rem & 3;
        const float* W2b = W2 + blk * 128 * 224;
        unsigned short* dst = W2P + ((size_t)idx * 64 + lane) * 8;
        int ch = 16 * mt + lr;
        #pragma unroll
        for (int i = 0; i < 8; ++i) {
            int k = 32 * ks + 8 * t4 + i;
            dst[i] = (ch < NWC) ? f2bf(W2b[k * NWC + ch]) : (unsigned short)0;
        }
    }
}

// ---------------- init: s ; zero v (SoA) -----------------------------------------------------
__global__ __launch_bounds__(128) void eae_init_kernel(
    const int* __restrict__ z, const float* __restrict__ mask, const int* __restrict__ absorber,
    const float* __restrict__ z_emb, const float* __restrict__ W_in,
    float* __restrict__ s, float* __restrict__ v)
{
    int n = blockIdx.x;
    int t = threadIdx.x;
    int b = n >> 6;
    int ni = n & 63;
    float fm = mask[n];
    int zi = z[n];
    float af = (absorber[b] == ni) ? 1.0f : 0.0f;
    if (t < 64) {
        const float* ze = z_emb + zi * 64;
        float acc = 0.0f;
        #pragma unroll 4
        for (int k = 0; k < 64; ++k) acc += ze[k] * W_in[k * 64 + t];
        acc += af * W_in[64 * 64 + t];
        s[n * 64 + t] = acc * fm;
    }
    if (t < 96) v[n * 96 + t] = 0.0f;
}

// ================= shared device bodies ======================================================
__device__ __forceinline__ void eae_wgemm_body(
    char* smem, int tid, int tile0, int tstride,
    const float4* __restrict__ edata, const unsigned short* __restrict__ rbf_g,
    const unsigned short* __restrict__ W1Pb, const float* __restrict__ b1b,
    const unsigned short* __restrict__ W2Pb, const float* __restrict__ b2b,
    unsigned short* __restrict__ wbuf, int E, int ntiles)
{
    unsigned short* h_lds  = (unsigned short*)smem;            // 16KB
    unsigned short* w_tile = (unsigned short*)(smem + 16384);  // 28KB
    char* hb = (char*)h_lds;

    const int wid  = tid >> 6;
    const int lane = tid & 63;
    const int t4   = lane >> 4;
    const int lr   = lane & 15;
    const int swz  = (lr & 7) << 4;

    bfrag8 a1 = *reinterpret_cast<const bfrag8*>(W1Pb + ((size_t)wid * 64 + lane) * 8);
    float b1v[4];
    #pragma unroll
    for (int r = 0; r < 4; ++r) b1v[r] = b1b[16 * wid + 4 * t4 + r];

    bfrag8 a2[2][4];
    float b2v[2][4];
    #pragma unroll
    for (int m = 0; m < 2; ++m) {
        int mt = 2 * wid + m;
        #pragma unroll
        for (int ks = 0; ks < 4; ++ks)
            a2[m][ks] = *reinterpret_cast<const bfrag8*>(W2Pb + (((size_t)mt * 4 + ks) * 64 + lane) * 8);
        #pragma unroll
        for (int r = 0; r < 4; ++r) {
            int chr = 16 * mt + 4 * t4 + r;
            b2v[m][r] = (chr < NWC) ? b2b[chr] : 0.0f;
        }
    }

    for (int tile = tile0; tile < ntiles; tile += tstride) {
        const int e0 = tile * 64;

        float env4[4];
        bfrag8 brbf[4];
        #pragma unroll
        for (int et = 0; et < 4; ++et) {
            int eg = e0 + 16 * et + lr;
            int ie = (eg < E) ? eg : (E - 1);
            env4[et] = edata[ie].w;
            brbf[et] = *reinterpret_cast<const bfrag8*>(rbf_g + (size_t)ie * RBFD + 8 * t4);
        }

        facc4 acc1[4];
        #pragma unroll
        for (int et = 0; et < 4; ++et) { facc4 zz = {0.f,0.f,0.f,0.f}; acc1[et] = zz; }
        #pragma unroll
        for (int et = 0; et < 4; ++et)
            acc1[et] = __builtin_amdgcn_mfma_f32_16x16x32_bf16(a1, brbf[et], acc1[et], 0, 0, 0);

        {
            int ch0b = (16 * wid + 4 * t4) * 2;
            #pragma unroll
            for (int et = 0; et < 4; ++et) {
                int e = 16 * et + lr;
                unsigned short hv[4];
                #pragma unroll
                for (int r = 0; r < 4; ++r)
                    hv[r] = f2bf(siluf(acc1[et][r] + b1v[r]));
                uint2 pk;
                pk.x = (unsigned int)hv[0] | ((unsigned int)hv[1] << 16);
                pk.y = (unsigned int)hv[2] | ((unsigned int)hv[3] << 16);
                *reinterpret_cast<uint2*>(hb + e * 256 + (ch0b ^ swz)) = pk;
            }
        }
        __syncthreads();

        facc4 acc2[2][4];
        #pragma unroll
        for (int m = 0; m < 2; ++m)
            #pragma unroll
            for (int et = 0; et < 4; ++et) { facc4 zz = {0.f,0.f,0.f,0.f}; acc2[m][et] = zz; }
        #pragma unroll
        for (int et = 0; et < 4; ++et) {
            int e = 16 * et + lr;
            bfrag8 hf[4];
            #pragma unroll
            for (int ks = 0; ks < 4; ++ks)
                hf[ks] = *reinterpret_cast<const bfrag8*>(hb + e * 256 + ((64 * ks + 16 * t4) ^ swz));
            #pragma unroll
            for (int m = 0; m < 2; ++m)
                #pragma unroll
                for (int ks = 0; ks < 4; ++ks)
                    acc2[m][et] = __builtin_amdgcn_mfma_f32_16x16x32_bf16(a2[m][ks], hf[ks], acc2[m][et], 0, 0, 0);
        }

        #pragma unroll
        for (int m = 0; m < 2; ++m) {
            int mt = 2 * wid + m;
            if (mt < 14) {
                int cb = 16 * mt + 4 * t4;
                #pragma unroll
                for (int et = 0; et < 4; ++et) {
                    int e = 16 * et + lr;
                    unsigned short hv[4];
                    #pragma unroll
                    for (int r = 0; r < 4; ++r)
                        hv[r] = f2bf((acc2[m][et][r] + b2v[m][r]) * env4[et]);
                    uint2 pk;
                    pk.x = (unsigned int)hv[0] | ((unsigned int)hv[1] << 16);
                    pk.y = (unsigned int)hv[2] | ((unsigned int)hv[3] << 16);
                    *reinterpret_cast<uint2*>(w_tile + e * NWC + cb) = pk;
                }
            }
        }
        __syncthreads();

        if (e0 + 64 <= E) {
            unsigned short* dst = wbuf + (size_t)e0 * NWC;
            for (int idx = tid; idx < 64 * NWC / 8; idx += 512) {
                uint4 d = *reinterpret_cast<const uint4*>(w_tile + idx * 8);
                *reinterpret_cast<uint4*>(dst + idx * 8) = d;
            }
        } else {
            int rem = (E - e0) * NWC;
            unsigned short* dst = wbuf + (size_t)e0 * NWC;
            for (int idx = tid; idx < rem; idx += 512) dst[idx] = w_tile[idx];
        }
        __syncthreads();
    }
}

#define EAE_COMPUTE(ed, wp, g0, g1, g2)                                                         \
    do {                                                                                        \
        float yx = ed.x, yy = ed.y, yz = ed.z;                                                  \
        float w0 = bf2f(wp.x & 0xffffu), w1 = bf2f(wp.x >> 16);                                 \
        float w2 = bf2f(wp.y & 0xffffu), w3 = bf2f(wp.y >> 16);                                 \
        if (kcls == 0) {                                                                        \
            a00 += w0 * g0.x; a10 += w1 * g0.y; a20 += w2 * g0.z; a30 += w3 * g0.w;             \
        } else if (kcls == 1) {                                                                 \
            a00 += w0 * (g0.x * yx + g1.x * yy + g2.x * yz) * IS3;                              \
            a10 += w1 * (g0.y * yx + g1.y * yy + g2.y * yz) * IS3;                              \
            a20 += w2 * (g0.z * yx + g1.z * yy + g2.z * yz) * IS3;                              \
            a30 += w3 * (g0.w * yx + g1.w * yy + g2.w * yz) * IS3;                              \
        } else if (kcls == 2) {                                                                 \
            float t0 = w0 * g0.x, t1 = w1 * g0.y, t2 = w2 * g0.z, t3 = w3 * g0.w;               \
            a00 += t0 * yx; a01 += t0 * yy; a02 += t0 * yz;                                     \
            a10 += t1 * yx; a11 += t1 * yy; a12 += t1 * yz;                                     \
            a20 += t2 * yx; a21 += t2 * yy; a22 += t2 * yz;                                     \
            a30 += t3 * yx; a31 += t3 * yy; a32 += t3 * yz;                                     \
        } else if (kcls == 3) {                                                                 \
            a00 += w0 * g0.x; a01 += w0 * g1.x; a02 += w0 * g2.x;                               \
            a10 += w1 * g0.y; a11 += w1 * g1.y; a12 += w1 * g2.y;                               \
            a20 += w2 * g0.z; a21 += w2 * g1.z; a22 += w2 * g2.z;                               \
            a30 += w3 * g0.w; a31 += w3 * g1.w; a32 += w3 * g2.w;                               \
        } else if (kcls == 4) {                                                                 \
            float s0 = w0 * IS2, s1 = w1 * IS2, s2 = w2 * IS2, s3 = w3 * IS2;                   \
            a00 += s0 * (g1.x * yz - g2.x * yy); a01 += s0 * (g2.x * yx - g0.x * yz); a02 += s0 * (g0.x * yy - g1.x * yx); \
            a10 += s1 * (g1.y * yz - g2.y * yy); a11 += s1 * (g2.y * yx - g0.y * yz); a12 += s1 * (g0.y * yy - g1.y * yx); \
            a20 += s2 * (g1.z * yz - g2.z * yy); a21 += s2 * (g2.z * yx - g0.z * yz); a22 += s2 * (g0.z * yy - g1.z * yx); \
            a30 += s3 * (g1.w * yz - g2.w * yy); a31 += s3 * (g2.w * yx - g0.w * yz); a32 += s3 * (g0.w * yy - g1.w * yx); \
        }                                                                                       \
    } while (0)

#define EAE_LOADS(SUF, idx)                                                                     \
    int ie##SUF = ebeg + (idx);                                                                 \
    int src##SUF = esrc[ie##SUF];                                                               \
    float4 ed##SUF = edata[ie##SUF];                                                            \
    uint2 wp##SUF = *reinterpret_cast<const uint2*>(wbuf + (size_t)ie##SUF * NWC + wc);         \
    const float* base##SUF = useS ? (s_in + src##SUF * CSC) : (v_in + src##SUF * 96);           \
    float4 g0##SUF = *reinterpret_cast<const float4*>(base##SUF + coff);                        \
    float4 g1##SUF, g2##SUF;                                                                    \
    if (!useS) {                                                                                \
        g1##SUF = *reinterpret_cast<const float4*>(base##SUF + 32 + coff);                      \
        g2##SUF = *reinterpret_cast<const float4*>(base##SUF + 64 + coff);                      \
    }

__device__ __forceinline__ void eae_gather_body(
    float* shbase, int n, int t,
    const int* __restrict__ row_ptr, const float4* __restrict__ edata,
    const int* __restrict__ esrc, const unsigned short* __restrict__ wbuf,
    const float* __restrict__ s_in, const float* __restrict__ v_in,
    float* __restrict__ aggs, float* __restrict__ aggv)
{
    const int wq = t >> 6;
    const int l  = t & 63;
    const int ch0 = 4 * l;

    const float IS3 = 0.57735026918962576f;
    const float IS2 = 0.70710678118654752f;

    int kcls; bool useS; int coff;
    if (l < 16)      { kcls = 0; useS = true;  coff = ch0; }
    else if (l < 24) { kcls = 1; useS = false; coff = ch0 - 64; }
    else if (l < 40) { kcls = 2; useS = true;  coff = ch0 - 96; }
    else if (l < 48) { kcls = 3; useS = false; coff = ch0 - 160; }
    else if (l < 56) { kcls = 4; useS = false; coff = ch0 - 192; }
    else             { kcls = 5; useS = true;  coff = 0; }
    const int wc = (l < 56) ? ch0 : 0;

    const int ebeg = row_ptr[n];
    const int ecnt = row_ptr[n + 1] - ebeg;
    int per = (ecnt + 3) >> 2;
    int i0 = wq * per; if (i0 > ecnt) i0 = ecnt;
    int i1 = i0 + per; if (i1 > ecnt) i1 = ecnt;

    float a00=0.f,a01=0.f,a02=0.f, a10=0.f,a11=0.f,a12=0.f;
    float a20=0.f,a21=0.f,a22=0.f, a30=0.f,a31=0.f,a32=0.f;

    int i = i0;
    for (; i + 3 < i1; i += 4) {
        EAE_LOADS(A, i);
        EAE_LOADS(B, i + 1);
        EAE_LOADS(C, i + 2);
        EAE_LOADS(D, i + 3);
        EAE_COMPUTE(edA, wpA, g0A, g1A, g2A);
        EAE_COMPUTE(edB, wpB, g0B, g1B, g2B);
        EAE_COMPUTE(edC, wpC, g0C, g1C, g2C);
        EAE_COMPUTE(edD, wpD, g0D, g1D, g2D);
    }
    for (; i < i1; ++i) {
        EAE_LOADS(A, i);
        EAE_COMPUTE(edA, wpA, g0A, g1A, g2A);
    }

    float* shw = shbase + wq * 480;
    if (kcls == 0) {
        shw[ch0 + 0] = a00; shw[ch0 + 1] = a10; shw[ch0 + 2] = a20; shw[ch0 + 3] = a30;
    } else if (kcls == 1) {
        shw[64 + coff + 0] = a00; shw[64 + coff + 1] = a10; shw[64 + coff + 2] = a20; shw[64 + coff + 3] = a30;
    } else if (kcls == 2) {
        int c = coff;
        shw[96 + 0 * 128 + c + 0] = a00; shw[96 + 1 * 128 + c + 0] = a01; shw[96 + 2 * 128 + c + 0] = a02;
        shw[96 + 0 * 128 + c + 1] = a10; shw[96 + 1 * 128 + c + 1] = a11; shw[96 + 2 * 128 + c + 1] = a12;
        shw[96 + 0 * 128 + c + 2] = a20; shw[96 + 1 * 128 + c + 2] = a21; shw[96 + 2 * 128 + c + 2] = a22;
        shw[96 + 0 * 128 + c + 3] = a30; shw[96 + 1 * 128 + c + 3] = a31; shw[96 + 2 * 128 + c + 3] = a32;
    } else if (kcls == 3) {
        int c = 64 + coff;
        shw[96 + 0 * 128 + c + 0] = a00; shw[96 + 1 * 128 + c + 0] = a01; shw[96 + 2 * 128 + c + 0] = a02;
        shw[96 + 0 * 128 + c + 1] = a10; shw[96 + 1 * 128 + c + 1] = a11; shw[96 + 2 * 128 + c + 1] = a12;
        shw[96 + 0 * 128 + c + 2] = a20; shw[96 + 1 * 128 + c + 2] = a21; shw[96 + 2 * 128 + c + 2] = a22;
        shw[96 + 0 * 128 + c + 3] = a30; shw[96 + 1 * 128 + c + 3] = a31; shw[96 + 2 * 128 + c + 3] = a32;
    } else if (kcls == 4) {
        int c = 96 + coff;
        shw[96 + 0 * 128 + c + 0] = a00; shw[96 + 1 * 128 + c + 0] = a01; shw[96 + 2 * 128 + c + 0] = a02;
        shw[96 + 0 * 128 + c + 1] = a10; shw[96 + 1 * 128 + c + 1] = a11; shw[96 + 2 * 128 + c + 1] = a12;
        shw[96 + 0 * 128 + c + 2] = a20; shw[96 + 1 * 128 + c + 2] = a21; shw[96 + 2 * 128 + c + 2] = a22;
        shw[96 + 0 * 128 + c + 3] = a30; shw[96 + 1 * 128 + c + 3] = a31; shw[96 + 2 * 128 + c + 3] = a32;
    }
    __syncthreads();

    for (int j = t; j < 480; j += 256) {
        float sum = shbase[j] + shbase[480 + j] + shbase[960 + j] + shbase[1440 + j];
        if (j < 96) aggs[n * 96 + j] = sum;
        else        aggv[n * 384 + (j - 96)] = sum;
    }
}

// ---------------- standalone wgemm (dispatch 0 + fallback path) ------------------------------
__global__ __launch_bounds__(512) void eae_wgemm_kernel(
    const float4* __restrict__ edata, const unsigned short* __restrict__ rbf_g,
    const unsigned short* __restrict__ W1Pb, const float* __restrict__ b1b,
    const unsigned short* __restrict__ W2Pb, const float* __restrict__ b2b,
    unsigned short* __restrict__ wbuf, int E, int ntiles)
{
    __shared__ __align__(16) char smem[45056];
    eae_wgemm_body(smem, threadIdx.x, blockIdx.x, gridDim.x,
                   edata, rbf_g, W1Pb, b1b, W2Pb, b2b, wbuf, E, ntiles);
}

// ---------------- standalone gather (fallback path) ------------------------------------------
__global__ __launch_bounds__(256) void eae_gather_kernel(
    const int* __restrict__ row_ptr,
    const float4* __restrict__ edata, const int* __restrict__ esrc,
    const unsigned short* __restrict__ wbuf,
    const float* __restrict__ s_in, const float* __restrict__ v_in,
    float* __restrict__ aggs, float* __restrict__ aggv)
{
    __shared__ float sh[4 * 480];
    eae_gather_body(sh, blockIdx.x, threadIdx.x, row_ptr, edata, esrc, wbuf,
                    s_in, v_in, aggs, aggv);
}

// ---------------- fat kernel: gather(blk) blocks + wgemm(blk+1) blocks in ONE dispatch -------
__global__ __launch_bounds__(512) void eae_fat_kernel(
    const int* __restrict__ row_ptr, const float4* __restrict__ edata,
    const int* __restrict__ esrc, const unsigned short* __restrict__ wbuf_r,
    const float* __restrict__ s_in, const float* __restrict__ v_in,
    float* __restrict__ aggs, float* __restrict__ aggv, int ngblk, int BN,
    const unsigned short* __restrict__ rbf_g,
    const unsigned short* __restrict__ W1Pb, const float* __restrict__ b1b,
    const unsigned short* __restrict__ W2Pb, const float* __restrict__ b2b,
    unsigned short* __restrict__ wbuf_w, int E, int ntiles)
{
    __shared__ __align__(16) char smem[45056];
    int bid = blockIdx.x;
    int tid = threadIdx.x;
    if (bid < ngblk) {
        int half = tid >> 8;          // 0/1: two nodes per block
        int t = tid & 255;
        int n = 2 * bid + half;
        float* shbase = (float*)smem + half * 4 * 480;
        if (n < BN) {
            eae_gather_body(shbase, n, t, row_ptr, edata, esrc, wbuf_r,
                            s_in, v_in, aggs, aggv);
        } else {
            __syncthreads();          // match gather_body's single barrier
        }
    } else {
        eae_wgemm_body(smem, tid, bid - ngblk, gridDim.x - ngblk,
                       edata, rbf_g, W1Pb, b1b, W2Pb, b2b, wbuf_w, E, ntiles);
    }
}

// ---------------- node update (SoA v/aggv) ---------------------------------------------------
__global__ __launch_bounds__(128) void eae_node_kernel(
    const float* __restrict__ Ws, const float* __restrict__ Wv, const float* __restrict__ Wg,
    const float* __restrict__ alpha,
    float* __restrict__ s, float* __restrict__ v,
    const float* __restrict__ aggs, const float* __restrict__ aggv, int blk)
{
    int n = blockIdx.x;
    int t = threadIdx.x;
    __shared__ float sh_as[96];
    __shared__ float sh_av[384];
    __shared__ float sh_us[64];
    __shared__ float sh_g[32];

    for (int i = t; i < 96; i += 128) sh_as[i] = aggs[n * 96 + i];
    for (int i = t; i < 384; i += 128) sh_av[i] = aggv[n * 384 + i];
    __syncthreads();

    float a = alpha[blk];
    const float* Wsb = Ws + blk * 96 * 64;
    const float* Wvb = Wv + blk * 128 * 32;
    const float* Wgb = Wg + blk * 64 * 32;

    if (t < 64) {
        float acc = 0.0f;
        #pragma unroll 4
        for (int j = 0; j < 96; ++j) acc += sh_as[j] * Wsb[j * 64 + t];
        sh_us[t] = siluf(acc);
    }
    __syncthreads();
    if (t < 32) {
        float acc = 0.0f;
        #pragma unroll 4
        for (int j = 0; j < 64; ++j) acc += sh_us[j] * Wgb[j * 32 + t];
        sh_g[t] = sigmf(acc);
    }
    if (t < 64) s[n * 64 + t] += a * sh_us[t];
    __syncthreads();
    if (t < 96) {
        int d = t >> 5;
        int c = t & 31;
        float acc = 0.0f;
        #pragma unroll 4
        for (int j = 0; j < 128; ++j) acc += sh_av[d * 128 + j] * Wvb[j * 32 + c];
        v[n * 96 + d * 32 + c] += a * sh_g[c] * acc;
    }
}

// ---------------- final: IrrepNorm + mask + pack output --------------------------------------
__global__ __launch_bounds__(64) void eae_final_kernel(
    const float* __restrict__ mask, const float* __restrict__ s, const float* __restrict__ v,
    float* __restrict__ out)
{
    int n = blockIdx.x;
    int t = threadIdx.x;
    float fm = mask[n];

    float sv = s[n * 64 + t];
    float ss = sv * sv;
    #pragma unroll
    for (int o = 32; o >= 1; o >>= 1) ss += __shfl_xor(ss, o);
    float sn = sv / sqrtf(ss / 64.0f + 1e-6f);
    out[n * 160 + t] = sn * fm;

    float vx = (t < 32) ? v[n * 96 + t]      : 0.0f;
    float vy = (t < 32) ? v[n * 96 + 32 + t] : 0.0f;
    float vz = (t < 32) ? v[n * 96 + 64 + t] : 0.0f;
    float vs2 = vx * vx + vy * vy + vz * vz;
    #pragma unroll
    for (int o = 32; o >= 1; o >>= 1) vs2 += __shfl_xor(vs2, o);
    float scale = fm / sqrtf(vs2 / 32.0f + 1e-6f);
    if (t < 32) {
        out[n * 160 + 64 + t * 3 + 0] = vx * scale;
        out[n * 160 + 64 + t * 3 + 1] = vy * scale;
        out[n * 160 + 64 + t * 3 + 2] = vz * scale;
    }
}

extern "C" void kernel_launch(void* const* d_in, const int* in_sizes, int n_in,
                              void* d_out, int out_size, void* d_ws, size_t ws_size,
                              hipStream_t stream) {
    const int*   z           = (const int*)d_in[0];
    const float* mask        = (const float*)d_in[1];
    const int*   absorber    = (const int*)d_in[2];
    const int*   edge_src    = (const int*)d_in[3];
    const int*   edge_dst    = (const int*)d_in[4];
    const float* edge_weight = (const float*)d_in[5];
    const float* edge_vec    = (const float*)d_in[6];
    const float* z_emb       = (const float*)d_in[7];
    const float* W_in        = (const float*)d_in[8];
    const float* W1          = (const float*)d_in[9];
    const float* b1          = (const float*)d_in[10];
    const float* W2          = (const float*)d_in[11];
    const float* b2          = (const float*)d_in[12];
    const float* Ws          = (const float*)d_in[13];
    const float* Wv          = (const float*)d_in[14];
    const float* Wg          = (const float*)d_in[15];
    const float* alpha       = (const float*)d_in[16];
    float* out = (float*)d_out;

    const int BN = in_sizes[0];    // 2048
    const int E  = in_sizes[3];    // 131072

    float* ws_f = (float*)d_ws;
    float4* edata = (float4*)ws_f;                        // E float4 = {yx,yy,yz,env}
    float* s    = ws_f + (size_t)E * 4;                   // BN*64
    float* v    = s + (size_t)BN * 64;                    // BN*96  SoA [3][32]
    float* aggs = v + (size_t)BN * 96;                    // BN*96
    float* aggv = aggs + (size_t)BN * 96;                 // BN*384 SoA [3][128]
    int*   iws  = (int*)(aggv + (size_t)BN * 384);
    int* esrc    = iws;                                   // E
    int* cnt     = esrc + E;                              // BN
    int* row_ptr = cnt + BN;                              // BN+4 (align pad)
    int* cursor  = row_ptr + BN + 4;                      // BN
    unsigned short* W1P = (unsigned short*)(cursor + BN); // 3*8*64*8
    unsigned short* W2P = W1P + 3 * 8 * 64 * 8;           // 3*64*64*8
    unsigned short* wbufA = W2P + 3 * 64 * 64 * 8;        // E*224 bf16 (~59 MB)
    unsigned short* rbf_g = wbufA + (size_t)E * NWC;      // E*32 bf16  (~8 MB)
    unsigned short* wbufB = rbf_g + (size_t)E * RBFD;     // E*224 bf16 (optional)

    size_t need2 = (size_t)((char*)(wbufB + (size_t)E * NWC) - (char*)d_ws);
    bool overlap = (ws_size >= need2);
    if (!overlap) wbufB = wbufA;

    eae_zero_int<<<(BN + 255) / 256, 256, 0, stream>>>(cnt, BN);
    eae_hist_kernel<<<(E + 255) / 256, 256, 0, stream>>>(edge_dst, cnt, E);
    eae_scan_kernel<<<1, 256, 0, stream>>>(cnt, row_ptr, cursor, BN);
    eae_scatter_kernel<<<(E + 255) / 256, 256, 0, stream>>>(
        edge_dst, edge_src, edge_weight, edge_vec, cursor, edata, esrc, rbf_g, E);
    eae_pack_kernel<<<216, 64, 0, stream>>>(W1, W2, W1P, W2P);

    eae_init_kernel<<<BN, 128, 0, stream>>>(z, mask, absorber, z_emb, W_in, s, v);

    int ntiles = (E + 63) / 64;
    if (overlap) {
        const int ngblk = BN / 2;  // 1024
        // dispatch 0: wgemm(blk0) -> A
        eae_wgemm_kernel<<<1024, 512, 0, stream>>>(
            edata, rbf_g, W1P, b1 + 0, W2P, b2 + 0, wbufA, E, ntiles);
        // fat: gather(0|A) || wgemm(1)->B
        eae_fat_kernel<<<ngblk + 1024, 512, 0, stream>>>(
            row_ptr, edata, esrc, wbufA, s, v, aggs, aggv, ngblk, BN,
            rbf_g, W1P + (size_t)1 * 8 * 64 * 8, b1 + 128,
            W2P + (size_t)1 * 64 * 64 * 8, b2 + 224, wbufB, E, ntiles);
        eae_node_kernel<<<BN, 128, 0, stream>>>(Ws, Wv, Wg, alpha, s, v, aggs, aggv, 0);
        // fat: gather(1|B) || wgemm(2)->A
        eae_fat_kernel<<<ngblk + 1024, 512, 0, stream>>>(
            row_ptr, edata, esrc, wbufB, s, v, aggs, aggv, ngblk, BN,
            rbf_g, W1P + (size_t)2 * 8 * 64 * 8, b1 + 256,
            W2P + (size_t)2 * 64 * 64 * 8, b2 + 448, wbufA, E, ntiles);
        eae_node_kernel<<<BN, 128, 0, stream>>>(Ws, Wv, Wg, alpha, s, v, aggs, aggv, 1);
        // fat: gather(2|A) only
        eae_fat_kernel<<<ngblk, 512, 0, stream>>>(
            row_ptr, edata, esrc, wbufA, s, v, aggs, aggv, ngblk, BN,
            rbf_g, W1P, b1, W2P, b2, wbufB, E, 0);
        eae_node_kernel<<<BN, 128, 0, stream>>>(Ws, Wv, Wg, alpha, s, v, aggs, aggv, 2);
    } else {
        for (int blk = 0; blk < 3; ++blk) {
            eae_wgemm_kernel<<<1024, 512, 0, stream>>>(
                edata, rbf_g,
                W1P + (size_t)blk * 8 * 64 * 8, b1 + (size_t)blk * 128,
                W2P + (size_t)blk * 64 * 64 * 8, b2 + (size_t)blk * 224,
                wbufA, E, ntiles);
            eae_gather_kernel<<<BN, 256, 0, stream>>>(
                row_ptr, edata, esrc, wbufA, s, v, aggs, aggv);
            eae_node_kernel<<<BN, 128, 0, stream>>>(Ws, Wv, Wg, alpha, s, v, aggs, aggv, blk);
        }
    }
    eae_final_kernel<<<BN, 64, 0, stream>>>(mask, s, v, out);
}

// Round 15
// 304.434 us; speedup vs baseline: 1.2712x; 1.2712x over previous
//
#include <hip/hip_runtime.h>

#define CSC 64
#define CVC 32
#define HIDC 128
#define NWC 224
#define RBFD 32
#define CUTF 5.0f

typedef __attribute__((ext_vector_type(8))) short bfrag8;
typedef __attribute__((ext_vector_type(4))) float facc4;

__device__ __forceinline__ unsigned short f2bf(float x) {
    union { float f; unsigned int u; } a; a.f = x;
    unsigned int u = a.u;
    return (unsigned short)((u + 0x7fffu + ((u >> 16) & 1u)) >> 16);
}
__device__ __forceinline__ float bf2f(unsigned int u16) {
    union { float f; unsigned int v; } x; x.v = u16 << 16; return x.f;
}

__device__ __forceinline__ float siluf(float x) { return x / (1.0f + __expf(-x)); }
__device__ __forceinline__ float sigmf(float x) { return 1.0f / (1.0f + __expf(-x)); }

// ---------------- CSR build ------------------------------------------------------------------
__global__ __launch_bounds__(256) void eae_hist_kernel(const int* __restrict__ edge_dst,
                                                       int* __restrict__ cnt, int E) {
    int e = blockIdx.x * 256 + threadIdx.x;
    if (e < E) atomicAdd(&cnt[edge_dst[e]], 1);
}

__global__ __launch_bounds__(256) void eae_scan_kernel(const int* __restrict__ cnt,
                                                       int* __restrict__ row_ptr,
                                                       int* __restrict__ cursor, int BN) {
    __shared__ int part[256];
    int t = threadIdx.x;
    int per = (BN + 255) / 256;
    int base = t * per;
    int local[16];
    int lsum = 0;
    for (int i = 0; i < per; ++i) {
        int idx = base + i;
        int c = (idx < BN) ? cnt[idx] : 0;
        local[i] = c; lsum += c;
    }
    part[t] = lsum;
    __syncthreads();
    if (t == 0) {
        int run = 0;
        for (int i = 0; i < 256; ++i) { int v = part[i]; part[i] = run; run += v; }
    }
    __syncthreads();
    int run = part[t];
    for (int i = 0; i < per; ++i) {
        int idx = base + i;
        if (idx < BN) { row_ptr[idx] = run; cursor[idx] = run; run += local[i]; }
    }
    if (t == 255) row_ptr[BN] = run;
}

// scatter + per-edge precompute: y (sqrt3-scaled unit vec) + env + 32 RBF bf16
__global__ __launch_bounds__(256) void eae_scatter_kernel(
    const int* __restrict__ edge_dst, const int* __restrict__ edge_src,
    const float* __restrict__ edge_weight, const float* __restrict__ edge_vec,
    int* __restrict__ cursor, float4* __restrict__ edata, int* __restrict__ esrc,
    unsigned short* __restrict__ rbf_g, int E) {
    int e = blockIdx.x * 256 + threadIdx.x;
    if (e < E) {
        int pos = atomicAdd(&cursor[edge_dst[e]], 1);
        const float SQ3 = 1.7320508075688772f;
        const float PIF = 3.14159265358979323846f;
        const float delta = CUTF / (RBFD - 1);
        const float inv_delta = 1.0f / delta;
        float el = edge_weight[e];
        float inv = 1.0f / fmaxf(el, 1e-8f);
        float4 d;
        d.x = SQ3 * edge_vec[3 * e + 0] * inv;
        d.y = SQ3 * edge_vec[3 * e + 1] * inv;
        d.z = SQ3 * edge_vec[3 * e + 2] * inv;
        d.w = (el < CUTF) ? 0.5f * (__cosf(PIF * el / CUTF) + 1.0f) : 0.0f;
        edata[pos] = d;
        esrc[pos] = edge_src[e];
        float dd = fminf(el, CUTF) * inv_delta;
        unsigned short* rp = rbf_g + (size_t)pos * RBFD;
        #pragma unroll
        for (int k = 0; k < RBFD; ++k) {
            float x = dd - (float)k;
            rp[k] = f2bf(__expf(-0.5f * x * x));
        }
    }
}

// ---------------- weight packing + cnt zero (merged) -----------------------------------------
__global__ __launch_bounds__(64) void eae_pack_kernel(
    const float* __restrict__ W1, const float* __restrict__ W2,
    unsigned short* __restrict__ W1P, unsigned short* __restrict__ W2P,
    int* __restrict__ cnt, int BN)
{
    int b = blockIdx.x;
    int lane = threadIdx.x;
    int t4 = lane >> 4, lr = lane & 15;
    if (b < 24) {
        int blk = b >> 3, mt = b & 7;
        const float* W1b = W1 + blk * 32 * 128;
        unsigned short* dst = W1P + ((size_t)b * 64 + lane) * 8;
        #pragma unroll
        for (int i = 0; i < 8; ++i) {
            int k = 8 * t4 + i;
            dst[i] = f2bf(W1b[k * HIDC + 16 * mt + lr]);
        }
    } else if (b < 216) {
        int idx = b - 24;
        int blk = idx >> 6, rem = idx & 63;
        int mt = rem >> 2, ks = rem & 3;
        const float* W2b = W2 + blk * 128 * 224;
        unsigned short* dst = W2P + ((size_t)idx * 64 + lane) * 8;
        int ch = 16 * mt + lr;
        #pragma unroll
        for (int i = 0; i < 8; ++i) {
            int k = 32 * ks + 8 * t4 + i;
            dst[i] = (ch < NWC) ? f2bf(W2b[k * NWC + ch]) : (unsigned short)0;
        }
    } else {
        for (int i = (b - 216) * 64 + lane; i < BN; i += 8 * 64) cnt[i] = 0;
    }
}

// ---------------- init: s ; zero v (SoA) -----------------------------------------------------
__global__ __launch_bounds__(128) void eae_init_kernel(
    const int* __restrict__ z, const float* __restrict__ mask, const int* __restrict__ absorber,
    const float* __restrict__ z_emb, const float* __restrict__ W_in,
    float* __restrict__ s, float* __restrict__ v)
{
    int n = blockIdx.x;
    int t = threadIdx.x;
    int b = n >> 6;
    int ni = n & 63;
    float fm = mask[n];
    int zi = z[n];
    float af = (absorber[b] == ni) ? 1.0f : 0.0f;
    if (t < 64) {
        const float* ze = z_emb + zi * 64;
        float acc = 0.0f;
        #pragma unroll 4
        for (int k = 0; k < 64; ++k) acc += ze[k] * W_in[k * 64 + t];
        acc += af * W_in[64 * 64 + t];
        s[n * 64 + t] = acc * fm;
    }
    if (t < 96) v[n * 96 + t] = 0.0f;
}

// ---------------- K1: dense radial-MLP GEMM; RBF fragments streamed from global --------------
__global__ __launch_bounds__(512) void eae_wgemm_kernel(
    const float4* __restrict__ edata, const unsigned short* __restrict__ rbf_g,
    const unsigned short* __restrict__ W1Pb, const float* __restrict__ b1b,
    const unsigned short* __restrict__ W2Pb, const float* __restrict__ b2b,
    unsigned short* __restrict__ wbuf, int E, int ntiles)
{
    __shared__ unsigned short h_lds[64 * 128];   // h[e][k] bf16, swizzled, 16KB
    __shared__ unsigned short w_tile[64 * NWC];  // w staging, 28KB
    char* hb = (char*)h_lds;

    const int tid  = threadIdx.x;
    const int wid  = tid >> 6;       // 0..7
    const int lane = tid & 63;
    const int t4   = lane >> 4;
    const int lr   = lane & 15;
    const int swz  = (lr & 7) << 4;

    bfrag8 a1 = *reinterpret_cast<const bfrag8*>(W1Pb + ((size_t)wid * 64 + lane) * 8);
    float b1v[4];
    #pragma unroll
    for (int r = 0; r < 4; ++r) b1v[r] = b1b[16 * wid + 4 * t4 + r];

    bfrag8 a2[2][4];
    float b2v[2][4];
    #pragma unroll
    for (int m = 0; m < 2; ++m) {
        int mt = 2 * wid + m;
        #pragma unroll
        for (int ks = 0; ks < 4; ++ks)
            a2[m][ks] = *reinterpret_cast<const bfrag8*>(W2Pb + (((size_t)mt * 4 + ks) * 64 + lane) * 8);
        #pragma unroll
        for (int r = 0; r < 4; ++r) {
            int chr = 16 * mt + 4 * t4 + r;
            b2v[m][r] = (chr < NWC) ? b2b[chr] : 0.0f;
        }
    }

    for (int tile = blockIdx.x; tile < ntiles; tile += gridDim.x) {
        const int e0 = tile * 64;

        float env4[4];
        bfrag8 brbf[4];
        #pragma unroll
        for (int et = 0; et < 4; ++et) {
            int eg = e0 + 16 * et + lr;
            int ie = (eg < E) ? eg : (E - 1);
            env4[et] = edata[ie].w;
            brbf[et] = *reinterpret_cast<const bfrag8*>(rbf_g + (size_t)ie * RBFD + 8 * t4);
        }

        // GEMM1
        facc4 acc1[4];
        #pragma unroll
        for (int et = 0; et < 4; ++et) { facc4 zz = {0.f,0.f,0.f,0.f}; acc1[et] = zz; }
        #pragma unroll
        for (int et = 0; et < 4; ++et)
            acc1[et] = __builtin_amdgcn_mfma_f32_16x16x32_bf16(a1, brbf[et], acc1[et], 0, 0, 0);

        // silu -> LDS (swizzled)
        {
            int ch0b = (16 * wid + 4 * t4) * 2;
            #pragma unroll
            for (int et = 0; et < 4; ++et) {
                int e = 16 * et + lr;
                unsigned short hv[4];
                #pragma unroll
                for (int r = 0; r < 4; ++r)
                    hv[r] = f2bf(siluf(acc1[et][r] + b1v[r]));
                uint2 pk;
                pk.x = (unsigned int)hv[0] | ((unsigned int)hv[1] << 16);
                pk.y = (unsigned int)hv[2] | ((unsigned int)hv[3] << 16);
                *reinterpret_cast<uint2*>(hb + e * 256 + (ch0b ^ swz)) = pk;
            }
        }
        __syncthreads();

        // GEMM2 + stage w into w_tile (LDS)
        facc4 acc2[2][4];
        #pragma unroll
        for (int m = 0; m < 2; ++m)
            #pragma unroll
            for (int et = 0; et < 4; ++et) { facc4 zz = {0.f,0.f,0.f,0.f}; acc2[m][et] = zz; }
        #pragma unroll
        for (int et = 0; et < 4; ++et) {
            int e = 16 * et + lr;
            bfrag8 hf[4];
            #pragma unroll
            for (int ks = 0; ks < 4; ++ks)
                hf[ks] = *reinterpret_cast<const bfrag8*>(hb + e * 256 + ((64 * ks + 16 * t4) ^ swz));
            #pragma unroll
            for (int m = 0; m < 2; ++m)
                #pragma unroll
                for (int ks = 0; ks < 4; ++ks)
                    acc2[m][et] = __builtin_amdgcn_mfma_f32_16x16x32_bf16(a2[m][ks], hf[ks], acc2[m][et], 0, 0, 0);
        }

        #pragma unroll
        for (int m = 0; m < 2; ++m) {
            int mt = 2 * wid + m;
            if (mt < 14) {
                int cb = 16 * mt + 4 * t4;
                #pragma unroll
                for (int et = 0; et < 4; ++et) {
                    int e = 16 * et + lr;
                    unsigned short hv[4];
                    #pragma unroll
                    for (int r = 0; r < 4; ++r)
                        hv[r] = f2bf((acc2[m][et][r] + b2v[m][r]) * env4[et]);
                    uint2 pk;
                    pk.x = (unsigned int)hv[0] | ((unsigned int)hv[1] << 16);
                    pk.y = (unsigned int)hv[2] | ((unsigned int)hv[3] << 16);
                    *reinterpret_cast<uint2*>(w_tile + e * NWC + cb) = pk;
                }
            }
        }
        __syncthreads();

        // coalesced copyout
        if (e0 + 64 <= E) {
            unsigned short* dst = wbuf + (size_t)e0 * NWC;
            for (int idx = tid; idx < 64 * NWC / 8; idx += 512) {
                uint4 d = *reinterpret_cast<const uint4*>(w_tile + idx * 8);
                *reinterpret_cast<uint4*>(dst + idx * 8) = d;
            }
        } else {
            int rem = (E - e0) * NWC;
            unsigned short* dst = wbuf + (size_t)e0 * NWC;
            for (int idx = tid; idx < rem; idx += 512) dst[idx] = w_tile[idx];
        }
        __syncthreads();
    }
}

// ---------------- K2: per-node gather — hoisted branchless loads + 2-way unroll --------------
#define EAE_COMPUTE(ed, wp, g0, g1, g2)                                                         \
    do {                                                                                        \
        float yx = ed.x, yy = ed.y, yz = ed.z;                                                  \
        float w0 = bf2f(wp.x & 0xffffu), w1 = bf2f(wp.x >> 16);                                 \
        float w2 = bf2f(wp.y & 0xffffu), w3 = bf2f(wp.y >> 16);                                 \
        if (kcls == 0) {                                                                        \
            a00 += w0 * g0.x; a10 += w1 * g0.y; a20 += w2 * g0.z; a30 += w3 * g0.w;             \
        } else if (kcls == 1) {                                                                 \
            a00 += w0 * (g0.x * yx + g1.x * yy + g2.x * yz) * IS3;                              \
            a10 += w1 * (g0.y * yx + g1.y * yy + g2.y * yz) * IS3;                              \
            a20 += w2 * (g0.z * yx + g1.z * yy + g2.z * yz) * IS3;                              \
            a30 += w3 * (g0.w * yx + g1.w * yy + g2.w * yz) * IS3;                              \
        } else if (kcls == 2) {                                                                 \
            float t0 = w0 * g0.x, t1 = w1 * g0.y, t2 = w2 * g0.z, t3 = w3 * g0.w;               \
            a00 += t0 * yx; a01 += t0 * yy; a02 += t0 * yz;                                     \
            a10 += t1 * yx; a11 += t1 * yy; a12 += t1 * yz;                                     \
            a20 += t2 * yx; a21 += t2 * yy; a22 += t2 * yz;                                     \
            a30 += t3 * yx; a31 += t3 * yy; a32 += t3 * yz;                                     \
        } else if (kcls == 3) {                                                                 \
            a00 += w0 * g0.x; a01 += w0 * g1.x; a02 += w0 * g2.x;                               \
            a10 += w1 * g0.y; a11 += w1 * g1.y; a12 += w1 * g2.y;                               \
            a20 += w2 * g0.z; a21 += w2 * g1.z; a22 += w2 * g2.z;                               \
            a30 += w3 * g0.w; a31 += w3 * g1.w; a32 += w3 * g2.w;                               \
        } else if (kcls == 4) {                                                                 \
            float s0 = w0 * IS2, s1 = w1 * IS2, s2 = w2 * IS2, s3 = w3 * IS2;                   \
            a00 += s0 * (g1.x * yz - g2.x * yy); a01 += s0 * (g2.x * yx - g0.x * yz); a02 += s0 * (g0.x * yy - g1.x * yx); \
            a10 += s1 * (g1.y * yz - g2.y * yy); a11 += s1 * (g2.y * yx - g0.y * yz); a12 += s1 * (g0.y * yy - g1.y * yx); \
            a20 += s2 * (g1.z * yz - g2.z * yy); a21 += s2 * (g2.z * yx - g0.z * yz); a22 += s2 * (g0.z * yy - g1.z * yx); \
            a30 += s3 * (g1.w * yz - g2.w * yy); a31 += s3 * (g2.w * yx - g0.w * yz); a32 += s3 * (g0.w * yy - g1.w * yx); \
        }                                                                                       \
    } while (0)

__global__ __launch_bounds__(256) void eae_gather_kernel(
    const int* __restrict__ row_ptr,
    const float4* __restrict__ edata, const int* __restrict__ esrc,
    const unsigned short* __restrict__ wbuf,
    const float* __restrict__ s, const float* __restrict__ v,
    float* __restrict__ aggs, float* __restrict__ aggv)
{
    __shared__ float sh[4][480];   // [wave][96 aggs | 384 aggv-SoA]

    const int n  = blockIdx.x;
    const int wq = threadIdx.x >> 6;
    const int l  = threadIdx.x & 63;
    const int ch0 = 4 * l;

    const float IS3 = 0.57735026918962576f;
    const float IS2 = 0.70710678118654752f;

    // per-lane class constants
    int kcls; bool useS; int coff;
    if (l < 16)      { kcls = 0; useS = true;  coff = ch0; }
    else if (l < 24) { kcls = 1; useS = false; coff = ch0 - 64; }
    else if (l < 40) { kcls = 2; useS = true;  coff = ch0 - 96; }
    else if (l < 48) { kcls = 3; useS = false; coff = ch0 - 160; }
    else if (l < 56) { kcls = 4; useS = false; coff = ch0 - 192; }
    else             { kcls = 5; useS = true;  coff = 0; }
    const int wc = (l < 56) ? ch0 : 0;

    const int ebeg = row_ptr[n];
    const int ecnt = row_ptr[n + 1] - ebeg;
    int per = (ecnt + 3) >> 2;
    int i0 = wq * per; if (i0 > ecnt) i0 = ecnt;
    int i1 = i0 + per; if (i1 > ecnt) i1 = ecnt;

    float a00=0.f,a01=0.f,a02=0.f, a10=0.f,a11=0.f,a12=0.f;
    float a20=0.f,a21=0.f,a22=0.f, a30=0.f,a31=0.f,a32=0.f;

    int i = i0;
    for (; i + 1 < i1; i += 2) {
        int ieA = ebeg + i, ieB = ebeg + i + 1;
        int srcA = esrc[ieA], srcB = esrc[ieB];
        float4 edA = edata[ieA], edB = edata[ieB];
        uint2 wpA = *reinterpret_cast<const uint2*>(wbuf + (size_t)ieA * NWC + wc);
        uint2 wpB = *reinterpret_cast<const uint2*>(wbuf + (size_t)ieB * NWC + wc);
        const float* baseA = useS ? (s + srcA * CSC) : (v + srcA * 96);
        const float* baseB = useS ? (s + srcB * CSC) : (v + srcB * 96);
        float4 g0A = *reinterpret_cast<const float4*>(baseA + coff);
        float4 g0B = *reinterpret_cast<const float4*>(baseB + coff);
        float4 g1A, g2A, g1B, g2B;
        if (!useS) {
            g1A = *reinterpret_cast<const float4*>(baseA + 32 + coff);
            g2A = *reinterpret_cast<const float4*>(baseA + 64 + coff);
            g1B = *reinterpret_cast<const float4*>(baseB + 32 + coff);
            g2B = *reinterpret_cast<const float4*>(baseB + 64 + coff);
        }
        EAE_COMPUTE(edA, wpA, g0A, g1A, g2A);
        EAE_COMPUTE(edB, wpB, g0B, g1B, g2B);
    }
    if (i < i1) {
        int ieA = ebeg + i;
        int srcA = esrc[ieA];
        float4 edA = edata[ieA];
        uint2 wpA = *reinterpret_cast<const uint2*>(wbuf + (size_t)ieA * NWC + wc);
        const float* baseA = useS ? (s + srcA * CSC) : (v + srcA * 96);
        float4 g0A = *reinterpret_cast<const float4*>(baseA + coff);
        float4 g1A, g2A;
        if (!useS) {
            g1A = *reinterpret_cast<const float4*>(baseA + 32 + coff);
            g2A = *reinterpret_cast<const float4*>(baseA + 64 + coff);
        }
        EAE_COMPUTE(edA, wpA, g0A, g1A, g2A);
    }

    // write per-wave partials into sh (flat layout: [0..95]=aggs, [96..479]=aggv SoA [3][128])
    float* shw = sh[wq];
    if (kcls == 0) {
        shw[ch0 + 0] = a00; shw[ch0 + 1] = a10; shw[ch0 + 2] = a20; shw[ch0 + 3] = a30;
    } else if (kcls == 1) {
        shw[64 + coff + 0] = a00; shw[64 + coff + 1] = a10; shw[64 + coff + 2] = a20; shw[64 + coff + 3] = a30;
    } else if (kcls == 2) {
        int c = coff;
        shw[96 + 0 * 128 + c + 0] = a00; shw[96 + 1 * 128 + c + 0] = a01; shw[96 + 2 * 128 + c + 0] = a02;
        shw[96 + 0 * 128 + c + 1] = a10; shw[96 + 1 * 128 + c + 1] = a11; shw[96 + 2 * 128 + c + 1] = a12;
        shw[96 + 0 * 128 + c + 2] = a20; shw[96 + 1 * 128 + c + 2] = a21; shw[96 + 2 * 128 + c + 2] = a22;
        shw[96 + 0 * 128 + c + 3] = a30; shw[96 + 1 * 128 + c + 3] = a31; shw[96 + 2 * 128 + c + 3] = a32;
    } else if (kcls == 3) {
        int c = 64 + coff;
        shw[96 + 0 * 128 + c + 0] = a00; shw[96 + 1 * 128 + c + 0] = a01; shw[96 + 2 * 128 + c + 0] = a02;
        shw[96 + 0 * 128 + c + 1] = a10; shw[96 + 1 * 128 + c + 1] = a11; shw[96 + 2 * 128 + c + 1] = a12;
        shw[96 + 0 * 128 + c + 2] = a20; shw[96 + 1 * 128 + c + 2] = a21; shw[96 + 2 * 128 + c + 2] = a22;
        shw[96 + 0 * 128 + c + 3] = a30; shw[96 + 1 * 128 + c + 3] = a31; shw[96 + 2 * 128 + c + 3] = a32;
    } else if (kcls == 4) {
        int c = 96 + coff;
        shw[96 + 0 * 128 + c + 0] = a00; shw[96 + 1 * 128 + c + 0] = a01; shw[96 + 2 * 128 + c + 0] = a02;
        shw[96 + 0 * 128 + c + 1] = a10; shw[96 + 1 * 128 + c + 1] = a11; shw[96 + 2 * 128 + c + 1] = a12;
        shw[96 + 0 * 128 + c + 2] = a20; shw[96 + 1 * 128 + c + 2] = a21; shw[96 + 2 * 128 + c + 2] = a22;
        shw[96 + 0 * 128 + c + 3] = a30; shw[96 + 1 * 128 + c + 3] = a31; shw[96 + 2 * 128 + c + 3] = a32;
    }
    __syncthreads();

    for (int j = threadIdx.x; j < 480; j += 256) {
        float sum = sh[0][j] + sh[1][j] + sh[2][j] + sh[3][j];
        if (j < 96) aggs[n * 96 + j] = sum;
        else        aggv[n * 384 + (j - 96)] = sum;
    }
}

// ---------------- node update (SoA v/aggv); last block fuses final norm ----------------------
__global__ __launch_bounds__(128) void eae_node_kernel(
    const float* __restrict__ Ws, const float* __restrict__ Wv, const float* __restrict__ Wg,
    const float* __restrict__ alpha,
    float* __restrict__ s, float* __restrict__ v,
    const float* __restrict__ aggs, const float* __restrict__ aggv, int blk,
    const float* __restrict__ mask, float* __restrict__ out, int last)
{
    int n = blockIdx.x;
    int t = threadIdx.x;
    __shared__ float sh_as[96];
    __shared__ float sh_av[384];
    __shared__ float sh_us[64];
    __shared__ float sh_g[32];
    __shared__ float sh_sv[96];

    for (int i = t; i < 96; i += 128) sh_as[i] = aggs[n * 96 + i];
    for (int i = t; i < 384; i += 128) sh_av[i] = aggv[n * 384 + i];
    __syncthreads();

    float a = alpha[blk];
    const float* Wsb = Ws + blk * 96 * 64;
    const float* Wvb = Wv + blk * 128 * 32;
    const float* Wgb = Wg + blk * 64 * 32;

    if (t < 64) {
        float acc = 0.0f;
        #pragma unroll 4
        for (int j = 0; j < 96; ++j) acc += sh_as[j] * Wsb[j * 64 + t];
        sh_us[t] = siluf(acc);
    }
    __syncthreads();
    if (t < 32) {
        float acc = 0.0f;
        #pragma unroll 4
        for (int j = 0; j < 64; ++j) acc += sh_us[j] * Wgb[j * 32 + t];
        sh_g[t] = sigmf(acc);
    }
    __syncthreads();

    float s_new = 0.0f, v_new = 0.0f;
    if (t < 64) s_new = s[n * 64 + t] + a * sh_us[t];
    if (t < 96) {
        int d = t >> 5;
        int c = t & 31;
        float acc = 0.0f;
        #pragma unroll 4
        for (int j = 0; j < 128; ++j) acc += sh_av[d * 128 + j] * Wvb[j * 32 + c];
        v_new = v[n * 96 + t] + a * sh_g[c] * acc;    // SoA index d*32+c == t
    }

    if (!last) {
        if (t < 64) s[n * 64 + t] = s_new;
        if (t < 96) v[n * 96 + t] = v_new;
    } else {
        if (t < 96) sh_sv[t] = v_new;
        __syncthreads();
        if (t < 64) {
            float fm = mask[n];
            float ss = s_new * s_new;
            #pragma unroll
            for (int o = 32; o >= 1; o >>= 1) ss += __shfl_xor(ss, o);
            out[n * 160 + t] = s_new / sqrtf(ss / 64.0f + 1e-6f) * fm;

            float vx = (t < 32) ? sh_sv[t]      : 0.0f;
            float vy = (t < 32) ? sh_sv[32 + t] : 0.0f;
            float vz = (t < 32) ? sh_sv[64 + t] : 0.0f;
            float vs2 = vx * vx + vy * vy + vz * vz;
            #pragma unroll
            for (int o = 32; o >= 1; o >>= 1) vs2 += __shfl_xor(vs2, o);
            float scale = fm / sqrtf(vs2 / 32.0f + 1e-6f);
            if (t < 32) {
                out[n * 160 + 64 + t * 3 + 0] = vx * scale;
                out[n * 160 + 64 + t * 3 + 1] = vy * scale;
                out[n * 160 + 64 + t * 3 + 2] = vz * scale;
            }
        }
    }
}

extern "C" void kernel_launch(void* const* d_in, const int* in_sizes, int n_in,
                              void* d_out, int out_size, void* d_ws, size_t ws_size,
                              hipStream_t stream) {
    const int*   z           = (const int*)d_in[0];
    const float* mask        = (const float*)d_in[1];
    const int*   absorber    = (const int*)d_in[2];
    const int*   edge_src    = (const int*)d_in[3];
    const int*   edge_dst    = (const int*)d_in[4];
    const float* edge_weight = (const float*)d_in[5];
    const float* edge_vec    = (const float*)d_in[6];
    const float* z_emb       = (const float*)d_in[7];
    const float* W_in        = (const float*)d_in[8];
    const float* W1          = (const float*)d_in[9];
    const float* b1          = (const float*)d_in[10];
    const float* W2          = (const float*)d_in[11];
    const float* b2          = (const float*)d_in[12];
    const float* Ws          = (const float*)d_in[13];
    const float* Wv          = (const float*)d_in[14];
    const float* Wg          = (const float*)d_in[15];
    const float* alpha       = (const float*)d_in[16];
    float* out = (float*)d_out;

    const int BN = in_sizes[0];    // 2048
    const int E  = in_sizes[3];    // 131072

    float* ws_f = (float*)d_ws;
    float4* edata = (float4*)ws_f;                        // E float4 = {yx,yy,yz,env}
    float* s    = ws_f + (size_t)E * 4;                   // BN*64
    float* v    = s + (size_t)BN * 64;                    // BN*96  SoA [3][32]
    float* aggs = v + (size_t)BN * 96;                    // BN*96
    float* aggv = aggs + (size_t)BN * 96;                 // BN*384 SoA [3][128]
    int*   iws  = (int*)(aggv + (size_t)BN * 384);
    int* esrc    = iws;                                   // E
    int* cnt     = esrc + E;                              // BN
    int* row_ptr = cnt + BN;                              // BN+4 (align pad)
    int* cursor  = row_ptr + BN + 4;                      // BN
    unsigned short* W1P = (unsigned short*)(cursor + BN); // 3*8*64*8   (16B-aligned)
    unsigned short* W2P = W1P + 3 * 8 * 64 * 8;           // 3*64*64*8
    unsigned short* wbuf = W2P + 3 * 64 * 64 * 8;         // E*224 bf16 (~59 MB)
    unsigned short* rbf_g = wbuf + (size_t)E * NWC;       // E*32 bf16  (~8 MB)

    eae_pack_kernel<<<224, 64, 0, stream>>>(W1, W2, W1P, W2P, cnt, BN);
    eae_hist_kernel<<<(E + 255) / 256, 256, 0, stream>>>(edge_dst, cnt, E);
    eae_scan_kernel<<<1, 256, 0, stream>>>(cnt, row_ptr, cursor, BN);
    eae_scatter_kernel<<<(E + 255) / 256, 256, 0, stream>>>(
        edge_dst, edge_src, edge_weight, edge_vec, cursor, edata, esrc, rbf_g, E);

    eae_init_kernel<<<BN, 128, 0, stream>>>(z, mask, absorber, z_emb, W_in, s, v);

    int ntiles = (E + 63) / 64;
    for (int blk = 0; blk < 3; ++blk) {
        eae_wgemm_kernel<<<512, 512, 0, stream>>>(
            edata, rbf_g,
            W1P + (size_t)blk * 8 * 64 * 8, b1 + (size_t)blk * 128,
            W2P + (size_t)blk * 64 * 64 * 8, b2 + (size_t)blk * 224,
            wbuf, E, ntiles);
        eae_gather_kernel<<<BN, 256, 0, stream>>>(
            row_ptr, edata, esrc, wbuf, s, v, aggs, aggv);
        eae_node_kernel<<<BN, 128, 0, stream>>>(
            Ws, Wv, Wg, alpha, s, v, aggs, aggv, blk, mask, out, (blk == 2) ? 1 : 0);
    }
}